// Round 1
// baseline (276.037 us; speedup 1.0000x reference)
//
#include <hip/hip_runtime.h>
#include <hip/hip_bf16.h>

// Causal attention B=2,H=12,S=2048,D=64 fp32 in/out.
// R12 = R11 + fused reduction (2 dispatches instead of 3):
//  - fa_reduce is gone. Each multi-chunk (bh,mt2) group finishes via a
//    device-scope atomic counter in workspace: after writing its partials,
//    every chunk block does threadfence+atomicAdd; the LAST chunk block
//    re-reads all chunks' partials (L2-hot: all chunks of a group share
//    bx&7 -> same XCD heuristic) and writes the normalized output.
//  - Counters (384 ints, one per (bh,mt2)) are zeroed by prep_kernel,
//    which is stream-ordered before fa11, so per-iteration re-poison of
//    the workspace is handled.
// Carried from R11: split-K chunks of 8 k-tiles (960 blocks), Q-direct
// load, single-chunk q-tiles (mt2<=3) normalize in-register, XCD swizzle
// (3 heads/XCD), double-buffered K/V + 1 barrier/iter, bf16 partial O +
// f32 l, BM=128, S^T=K*Q^T (packed b64 P stores), static-max base-2
// softmax, XOR-swizzled packed LDS (conflicts ~0).
// R9 lesson stands: K=16 register-P PV = 4x MFMA issue for half MACs; K=32
// LDS round-trip is cheaper.

#define SEQ 2048
#define DH 64
#define NHEADS 24
#define BN 64
#define LDK 72
#define ELEMS_PER_TENSOR (NHEADS * SEQ * DH)          // 3145728
#define NSLOT (NHEADS * 16 * 4)                       // 1536
#define NGROUP (NHEADS * 16)                          // 384
#define WS_KV    ((size_t)2 * ELEMS_PER_TENSOR * 2)   // 12582912 B
#define WS_FA11  (WS_KV + (size_t)NSLOT * 8192 * 2 + (size_t)NSLOT * 128 * 4)
#define WS_FA12  (WS_FA11 + (size_t)NGROUP * 4)

typedef float f32x4 __attribute__((ext_vector_type(4)));
typedef __bf16 bf16x8 __attribute__((ext_vector_type(8)));
typedef __bf16 bf16x4 __attribute__((ext_vector_type(4)));

#if __has_builtin(__builtin_amdgcn_exp2f)
#define EXP2F(x) __builtin_amdgcn_exp2f(x)
#else
#define EXP2F(x) exp2f(x)
#endif

#define QSCALE 0.1803368801111204f   // log2(e)/8: folds 1/sqrt(64) + base-2

// ---------------- pre-pass: K -> bf16, V -> bf16 transposed ----------------
__global__ __launch_bounds__(256)
void prep_kernel(const float* __restrict__ k, const float* __restrict__ v,
                 __bf16* __restrict__ ks, __bf16* __restrict__ vt,
                 int* __restrict__ cnt)
{
    __shared__ __bf16 T[64][LDK];
    const int bx = blockIdx.x;
    const int tid = threadIdx.x;
    if (bx == 0) {                         // zero the group-completion counters
        for (int i = tid; i < NGROUP; i += 256) cnt[i] = 0;
    }
    if (bx < 1536) {                       // K bf16 convert
        const int idx = (bx * 256 + tid) * 8;
        f32x4 a = *(const f32x4*)(k + idx);
        f32x4 b = *(const f32x4*)(k + idx + 4);
        bf16x8 o;
        #pragma unroll
        for (int j = 0; j < 4; ++j) { o[j] = (__bf16)a[j]; o[4 + j] = (__bf16)b[j]; }
        *(bf16x8*)(ks + idx) = o;
    } else {                               // V transpose to [bh][d][s]
        const int b2 = bx - 1536;
        const int bh = b2 >> 5;
        const int s0 = (b2 & 31) * 64;
        const int r = tid >> 2, c0 = (tid & 3) * 16;
        const float* vp = v + (size_t)bh * SEQ * DH + (size_t)(s0 + r) * DH + c0;
        __bf16 tmp[16];
        #pragma unroll
        for (int jj = 0; jj < 16; ++jj) tmp[jj] = (__bf16)vp[jj];
        *(bf16x8*)&T[r][c0]     = *(bf16x8*)&tmp[0];
        *(bf16x8*)&T[r][c0 + 8] = *(bf16x8*)&tmp[8];
        __syncthreads();
        const int d = tid >> 2, j0 = (tid & 3) * 16;
        __bf16 o[16];
        #pragma unroll
        for (int jj = 0; jj < 16; ++jj) o[jj] = T[j0 + jj][d];
        __bf16* op = vt + (size_t)bh * DH * SEQ + (size_t)d * SEQ + s0 + j0;
        *(bf16x8*)op       = *(bf16x8*)&o[0];
        *(bf16x8*)(op + 8) = *(bf16x8*)&o[8];
    }
}

// ---------------- main: BM=128, split-K(8), dbuf, XCD-swizzled, fused reduce ----------------
__global__ __launch_bounds__(256, 3)
void fa11_kernel(const float* __restrict__ q, const __bf16* __restrict__ ks,
                 const __bf16* __restrict__ vt,
                 __bf16* __restrict__ opart, float* __restrict__ lpart,
                 float* __restrict__ out, int* __restrict__ cnt)
{
    const int bx = blockIdx.x;             // 960 = 8 XCDs x 3 headgrp x 40
    const int xcd = bx & 7;
    const int sub = bx >> 3;               // 0..119
    const int bh = (sub / 40) * 8 + xcd;   // 3 heads pinned per XCD
    const int rem = 39 - (sub % 40);       // heavy-first within XCD
    int mt2, st;
    if      (rem >= 36) { mt2 = 15; st = 36; }
    else if (rem >= 32) { mt2 = 14; st = 32; }
    else if (rem >= 28) { mt2 = 13; st = 28; }
    else if (rem >= 24) { mt2 = 12; st = 24; }
    else if (rem >= 21) { mt2 = 11; st = 21; }
    else if (rem >= 18) { mt2 = 10; st = 18; }
    else if (rem >= 15) { mt2 = 9;  st = 15; }
    else if (rem >= 12) { mt2 = 8;  st = 12; }
    else if (rem >= 10) { mt2 = 7;  st = 10; }
    else if (rem >= 8)  { mt2 = 6;  st = 8; }
    else if (rem >= 6)  { mt2 = 5;  st = 6; }
    else if (rem >= 4)  { mt2 = 4;  st = 4; }
    else                { mt2 = rem; st = rem; }
    const int chunk = rem - st;
    const int jt0 = chunk * 8;
    const int jt_end = min(jt0 + 8, 2 * mt2 + 2);
    const int q0 = mt2 * 128;

    const int tid = threadIdx.x;
    const int w = tid >> 6, lane = tid & 63;
    const int g = lane >> 4, li = lane & 15;

    __shared__ __bf16 Ks[2][64 * 64];      // 16 KB double-buffered
    __shared__ __bf16 Vs[2][64 * 64];      // 16 KB
    __shared__ __bf16 Ps[4 * 32 * 64];     // 16 KB per-wave P tiles
    __shared__ int is_last;

    const __bf16* kh = ks + (size_t)bh * SEQ * DH;
    const __bf16* vh = vt + (size_t)bh * DH * SEQ;   // [d][s]

    // Q fragments: direct f32 load, scale+pack (B-operand layout for S^T)
    bf16x8 qf[2][2];
    #pragma unroll
    for (int a = 0; a < 2; ++a) {
        const float* qp = q + (size_t)bh * SEQ * DH +
                          (size_t)(q0 + w * 32 + a * 16 + li) * DH + g * 8;
        #pragma unroll
        for (int c = 0; c < 2; ++c) {
            f32x4 x0 = *(const f32x4*)(qp + c * 32);
            f32x4 x1 = *(const f32x4*)(qp + c * 32 + 4);
            #pragma unroll
            for (int j = 0; j < 4; ++j) {
                qf[a][c][j]     = (__bf16)(x0[j] * QSCALE);
                qf[a][c][4 + j] = (__bf16)(x1[j] * QSCALE);
            }
        }
    }

    bf16x8 ones;
    #pragma unroll
    for (int j = 0; j < 8; ++j) ones[j] = (__bf16)1.0f;

    f32x4 acc[2][4] = {};
    f32x4 accl[2] = {};

    const int srow0 = tid >> 3;            // staging: + s*32
    const int sg    = tid & 7;

    bf16x8 kr[2], vr[2];
    // ---- prologue: tile jt0 -> buf0; issue loads for jt0+1 ----
    #pragma unroll
    for (int s = 0; s < 2; ++s) {
        const int row = s * 32 + srow0;
        const int lg = sg ^ (row & 7);
        kr[s] = *(const bf16x8*)(kh + (size_t)(jt0 * BN + row) * DH + lg * 8);
        vr[s] = *(const bf16x8*)(vh + (size_t)row * SEQ + jt0 * BN + lg * 8);
    }
    #pragma unroll
    for (int s = 0; s < 2; ++s) {
        *(bf16x8*)((char*)Ks[0] + s * 4096 + tid * 16) = kr[s];
        *(bf16x8*)((char*)Vs[0] + s * 4096 + tid * 16) = vr[s];
    }
    if (jt0 + 1 < jt_end) {
        const int kv1 = (jt0 + 1) * BN;
        #pragma unroll
        for (int s = 0; s < 2; ++s) {
            const int row = s * 32 + srow0;
            const int lg = sg ^ (row & 7);
            kr[s] = *(const bf16x8*)(kh + (size_t)(kv1 + row) * DH + lg * 8);
            vr[s] = *(const bf16x8*)(vh + (size_t)row * SEQ + kv1 + lg * 8);
        }
    }
    __syncthreads();

    int buf = 0;
    for (int jt = jt0; jt < jt_end; ++jt) {
        // commit tile jt+1 (regs loaded a full iteration ago) into buf^1
        if (jt + 1 < jt_end) {
            #pragma unroll
            for (int s = 0; s < 2; ++s) {
                *(bf16x8*)((char*)Ks[buf ^ 1] + s * 4096 + tid * 16) = kr[s];
                *(bf16x8*)((char*)Vs[buf ^ 1] + s * 4096 + tid * 16) = vr[s];
            }
        }
        // issue loads for tile jt+2
        if (jt + 2 < jt_end) {
            const int kv2 = (jt + 2) * BN;
            #pragma unroll
            for (int s = 0; s < 2; ++s) {
                const int row = s * 32 + srow0;
                const int lg = sg ^ (row & 7);
                kr[s] = *(const bf16x8*)(kh + (size_t)(kv2 + row) * DH + lg * 8);
                vr[s] = *(const bf16x8*)(vh + (size_t)row * SEQ + kv2 + lg * 8);
            }
        }

        // ---- S^T = K * Q^T from buf ----
        const char* Kb = (const char*)Ks[buf];
        const char* Vb = (const char*)Vs[buf];
        float s4[2][4][4];                 // [a][t][r], kv = jt*64+t*16+g*4+r
        #pragma unroll
        for (int t = 0; t < 4; ++t) {
            f32x4 sa0 = {}, sa1 = {};
            #pragma unroll
            for (int c = 0; c < 2; ++c) {
                bf16x8 kf = *(const bf16x8*)(Kb +
                    (t * 16 + li) * 128 + (((c * 4 + g) ^ (li & 7)) << 4));
                sa0 = __builtin_amdgcn_mfma_f32_16x16x32_bf16(kf, qf[0][c], sa0, 0, 0, 0);
                sa1 = __builtin_amdgcn_mfma_f32_16x16x32_bf16(kf, qf[1][c], sa1, 0, 0, 0);
            }
            #pragma unroll
            for (int r = 0; r < 4; ++r) { s4[0][t][r] = sa0[r]; s4[1][t][r] = sa1[r]; }
        }

        if (jt >= 2 * mt2) {               // diagonal region: causal mask
            #pragma unroll
            for (int a = 0; a < 2; ++a) {
                const int qr = q0 + w * 32 + a * 16 + li;
                #pragma unroll
                for (int t = 0; t < 4; ++t) {
                    #pragma unroll
                    for (int r = 0; r < 4; ++r)
                        if (jt * 64 + t * 16 + g * 4 + r > qr) s4[a][t][r] = -1e30f;
                }
            }
        }

        // ---- p = 2^s -> packed b64 stores (4 consecutive kv per reg-quad) ----
        #pragma unroll
        for (int a = 0; a < 2; ++a) {
            const int row = a * 16 + li;
            #pragma unroll
            for (int t = 0; t < 4; ++t) {
                bf16x4 p4;
                #pragma unroll
                for (int r = 0; r < 4; ++r) p4[r] = (__bf16)EXP2F(s4[a][t][r]);
                const int pg = (t * 2 + (g >> 1)) ^ (li & 7);
                *(bf16x4*)((char*)Ps + w * 4096 + row * 128 + (pg << 4) + ((g & 1) << 3)) = p4;
            }
        }

        // ---- O += P V ; l += P * ones (pf as A-operand) ----
        #pragma unroll
        for (int c = 0; c < 2; ++c) {
            const int pgp = ((c * 4 + g) ^ (li & 7)) << 4;
            bf16x8 pf0 = *(const bf16x8*)((const char*)Ps + w * 4096 + li * 128 + pgp);
            bf16x8 pf1 = *(const bf16x8*)((const char*)Ps + w * 4096 + (16 + li) * 128 + pgp);
            accl[0] = __builtin_amdgcn_mfma_f32_16x16x32_bf16(pf0, ones, accl[0], 0, 0, 0);
            accl[1] = __builtin_amdgcn_mfma_f32_16x16x32_bf16(pf1, ones, accl[1], 0, 0, 0);
            #pragma unroll
            for (int t = 0; t < 4; ++t) {
                bf16x8 vf = *(const bf16x8*)(Vb + (t * 16 + li) * 128 + pgp);
                acc[0][t] = __builtin_amdgcn_mfma_f32_16x16x32_bf16(pf0, vf, acc[0][t], 0, 0, 0);
                acc[1][t] = __builtin_amdgcn_mfma_f32_16x16x32_bf16(pf1, vf, acc[1][t], 0, 0, 0);
            }
        }

        if (jt + 1 < jt_end) __syncthreads();   // readers of buf done; buf^1 ready
        buf ^= 1;
    }

    if (2 * mt2 + 2 <= 8) {
        // ---- single-chunk q-tile: normalize in-register, write out directly
        float* oh = out + (size_t)bh * SEQ * DH;
        #pragma unroll
        for (int a = 0; a < 2; ++a) {
            #pragma unroll
            for (int r = 0; r < 4; ++r) {
                const int row = q0 + w * 32 + a * 16 + g * 4 + r;
                const float inv = 1.0f / accl[a][r];
                float* op = oh + (size_t)row * DH + li;
                #pragma unroll
                for (int t = 0; t < 4; ++t) op[t * 16] = acc[a][t][r] * inv;
            }
        }
    } else {
        // ---- partials out (O in bf16; l in f32) ----
        const int group = bh * 16 + mt2;
        const int slot = group * 4 + chunk;
        __bf16* po = opart + (size_t)slot * 8192;
        #pragma unroll
        for (int a = 0; a < 2; ++a) {
            #pragma unroll
            for (int r = 0; r < 4; ++r) {
                const int row = w * 32 + a * 16 + g * 4 + r;
                __bf16* op = po + row * 64 + li;
                #pragma unroll
                for (int t = 0; t < 4; ++t) op[t * 16] = (__bf16)acc[a][t][r];
                if (li == 0) lpart[(size_t)slot * 128 + row] = accl[a][r];
            }
        }

        // ---- fused reduce: last chunk to finish sums all chunks, normalizes
        const int nc = (mt2 >> 2) + 1;     // ceil((2*mt2+2)/8)
        __threadfence();                   // release: partials device-visible
        __syncthreads();                   // all threads' stores+fences done
        if (tid == 0)
            is_last = (atomicAdd(&cnt[group], 1) == nc - 1);
        __syncthreads();
        if (is_last) {
            __threadfence();               // acquire: see other chunks' partials
            const int base = group * 4;
            #pragma unroll
            for (int rnd = 0; rnd < 8; ++rnd) {
                const int flat = rnd * 1024 + tid * 4;
                const int row = flat >> 6;
                float o0 = 0, o1 = 0, o2 = 0, o3 = 0, l = 0;
                for (int c = 0; c < nc; ++c) {
                    bf16x4 ov = *(const bf16x4*)(opart + (size_t)(base + c) * 8192 + flat);
                    o0 += (float)ov[0]; o1 += (float)ov[1]; o2 += (float)ov[2]; o3 += (float)ov[3];
                    l += lpart[(size_t)(base + c) * 128 + row];
                }
                const float inv = 1.0f / l;
                f32x4 res = { o0 * inv, o1 * inv, o2 * inv, o3 * inv };
                *(f32x4*)(out + (size_t)bh * SEQ * DH + (size_t)mt2 * 8192 + flat) = res;
            }
        }
    }
}

// ---------------- fallback: R1 self-contained kernel ----------------
__global__ __launch_bounds__(256, 2)
void fa_causal_kernel(const float* __restrict__ q, const float* __restrict__ k,
                      const float* __restrict__ v, float* __restrict__ out)
{
    const int mt = 31 - (blockIdx.x & 31);
    const int bh = blockIdx.x >> 5;
    const int tid = threadIdx.x;
    const int w = tid >> 6, lane = tid & 63;
    const int g = lane >> 4, li = lane & 15;
    const int m0 = mt * 64;
    __shared__ __bf16 KsF[BN][LDK];
    __shared__ __bf16 VsF[DH][LDK];
    __shared__ __bf16 PsF[4][16][LDK];
    const size_t head_off = (size_t)bh * SEQ * DH;
    const float* qh = q + head_off;
    const float* kh = k + head_off;
    const float* vh = v + head_off;
    float* oh = out + head_off;
    const int qrow = m0 + w * 16 + li;
    bf16x8 qf[2];
    {
        const float* qp = qh + (size_t)qrow * DH + g * 8;
        #pragma unroll
        for (int c = 0; c < 2; ++c) {
            const float* p = qp + c * 32;
            #pragma unroll
            for (int jj = 0; jj < 8; ++jj) qf[c][jj] = (__bf16)p[jj];
        }
    }
    f32x4 acc[4] = {};
    float mrow[4], lrow[4];
    #pragma unroll
    for (int r = 0; r < 4; ++r) { mrow[r] = -1e30f; lrow[r] = 0.0f; }
    const float scale = 0.125f;
    const int srow = tid >> 2, scol = (tid & 3) * 16;
    for (int jt = 0; jt <= mt; ++jt) {
        const int kv0 = jt * BN;
        __syncthreads();
        {
            const float* kp = kh + (size_t)(kv0 + srow) * DH + scol;
            __bf16 tmp[16];
            #pragma unroll
            for (int jj = 0; jj < 16; ++jj) tmp[jj] = (__bf16)kp[jj];
            *(bf16x8*)&KsF[srow][scol]     = *(bf16x8*)&tmp[0];
            *(bf16x8*)&KsF[srow][scol + 8] = *(bf16x8*)&tmp[8];
            const float* vp = vh + (size_t)(kv0 + srow) * DH + scol;
            #pragma unroll
            for (int jj = 0; jj < 16; ++jj) VsF[scol + jj][srow] = (__bf16)vp[jj];
        }
        __syncthreads();
        float s4[4][4];
        #pragma unroll
        for (int t = 0; t < 4; ++t) {
            f32x4 sa = {};
            #pragma unroll
            for (int c = 0; c < 2; ++c) {
                bf16x8 kfr = *(const bf16x8*)&KsF[t * 16 + li][c * 32 + g * 8];
                sa = __builtin_amdgcn_mfma_f32_16x16x32_bf16(qf[c], kfr, sa, 0, 0, 0);
            }
            #pragma unroll
            for (int r = 0; r < 4; ++r) s4[t][r] = sa[r] * scale;
        }
        if (jt == mt) {
            #pragma unroll
            for (int t = 0; t < 4; ++t) {
                const int col = kv0 + t * 16 + li;
                #pragma unroll
                for (int r = 0; r < 4; ++r)
                    if (col > m0 + w * 16 + g * 4 + r) s4[t][r] = -1e30f;
            }
        }
        #pragma unroll
        for (int r = 0; r < 4; ++r) {
            float mx = fmaxf(fmaxf(s4[0][r], s4[1][r]), fmaxf(s4[2][r], s4[3][r]));
            #pragma unroll
            for (int off = 1; off < 16; off <<= 1)
                mx = fmaxf(mx, __shfl_xor(mx, off, 64));
            const float mnew = fmaxf(mrow[r], mx);
            const float alpha = __expf(mrow[r] - mnew);
            mrow[r] = mnew;
            float ps = 0.0f;
            #pragma unroll
            for (int t = 0; t < 4; ++t) {
                const float p = __expf(s4[t][r] - mnew);
                s4[t][r] = p;
                ps += p;
            }
            #pragma unroll
            for (int off = 1; off < 16; off <<= 1)
                ps += __shfl_xor(ps, off, 64);
            lrow[r] = lrow[r] * alpha + ps;
            #pragma unroll
            for (int t = 0; t < 4; ++t) acc[t][r] *= alpha;
        }
        #pragma unroll
        for (int t = 0; t < 4; ++t)
            #pragma unroll
            for (int r = 0; r < 4; ++r)
                PsF[w][g * 4 + r][t * 16 + li] = (__bf16)s4[t][r];
        __syncthreads();
        #pragma unroll
        for (int c = 0; c < 2; ++c) {
            bf16x8 pf = *(const bf16x8*)&PsF[w][li][c * 32 + g * 8];
            #pragma unroll
            for (int t = 0; t < 4; ++t) {
                bf16x8 vfr = *(const bf16x8*)&VsF[t * 16 + li][c * 32 + g * 8];
                acc[t] = __builtin_amdgcn_mfma_f32_16x16x32_bf16(pf, vfr, acc[t], 0, 0, 0);
            }
        }
    }
    #pragma unroll
    for (int r = 0; r < 4; ++r) {
        const int row = m0 + w * 16 + g * 4 + r;
        const float inv = 1.0f / lrow[r];
        float* op = oh + (size_t)row * DH + li;
        #pragma unroll
        for (int t = 0; t < 4; ++t) op[t * 16] = acc[t][r] * inv;
    }
}

extern "C" void kernel_launch(void* const* d_in, const int* in_sizes, int n_in,
                              void* d_out, int out_size, void* d_ws, size_t ws_size,
                              hipStream_t stream) {
    (void)in_sizes; (void)n_in; (void)out_size;
    const float* q = (const float*)d_in[0];
    const float* k = (const float*)d_in[1];
    const float* v = (const float*)d_in[2];
    float* out = (float*)d_out;

    if (ws_size >= WS_FA12) {
        __bf16* ks = (__bf16*)d_ws;
        __bf16* vt = ks + ELEMS_PER_TENSOR;
        __bf16* opart = (__bf16*)((char*)d_ws + WS_KV);
        float* lpart = (float*)((char*)d_ws + WS_KV + (size_t)NSLOT * 8192 * 2);
        int* cnt = (int*)((char*)d_ws + WS_FA11);
        prep_kernel<<<dim3(1536 + 768), dim3(256), 0, stream>>>(k, v, ks, vt, cnt);
        fa11_kernel<<<dim3(960), dim3(256), 0, stream>>>(q, ks, vt, opart, lpart, out, cnt);
    } else {
        fa_causal_kernel<<<dim3(NHEADS * 32), dim3(256), 0, stream>>>(q, k, v, out);
    }
}

// Round 2
// 167.567 us; speedup vs baseline: 1.6473x; 1.6473x over previous
//
#include <hip/hip_runtime.h>
#include <hip/hip_bf16.h>

// Causal attention B=2,H=12,S=2048,D=64 fp32 in/out.
// R13 = R11 structure (3 dispatches; R12's device-fence fused reduce REVERTED:
// agent-scope threadfence = L2 writeback on non-coherent XCDs -> fa11 186us,
// 95% stall) with the main kernel's K/V LDS staging deleted:
//  - MFMA A/B fragment layouts (A: row=li,k=g*8+j; B: col=li,k=g*8+j) are
//    directly addressable in the prepped global ks [s][d] / vt [d][s] arrays:
//    16B/lane contiguous, 64B fully-used segments, L2-resident (1.5MB/XCD,
//    3 pinned heads), L1 absorbs the 4-waves-same-tile redundancy.
//  - Ps is per-wave -> NO __syncthreads anywhere in the kernel; no double
//    buffer; LDS 48.5KB -> 16KB. Kills the per-iter barrier+vmcnt(0) drain.
//  - __launch_bounds__(256,4): VGPR cap 128; grid (960 blocks ~ 15 waves/CU)
//    is the occupancy limit, all barrier-free.
// Carried: split-K chunks of 8 k-tiles (960 blocks), Q-direct load, single-
// chunk q-tiles (mt2<=3) normalize in-register, XCD swizzle (3 heads/XCD),
// bf16 partial O + f32 l, BM=128, S^T=K*Q^T, static-max base-2 softmax,
// XOR-swizzled packed Ps (conflict-free P round trip).
// R9 lesson stands: K=16 register-P PV = 4x MFMA issue for half MACs; LDS
// round-trip for P is cheaper. R12 lesson: no device-scope sync in hot loop.

#define SEQ 2048
#define DH 64
#define NHEADS 24
#define BN 64
#define LDK 72
#define ELEMS_PER_TENSOR (NHEADS * SEQ * DH)          // 3145728
#define NSLOT (NHEADS * 16 * 4)                       // 1536
#define WS_KV    ((size_t)2 * ELEMS_PER_TENSOR * 2)   // 12582912 B
#define WS_FA11  (WS_KV + (size_t)NSLOT * 8192 * 2 + (size_t)NSLOT * 128 * 4)

typedef float f32x4 __attribute__((ext_vector_type(4)));
typedef __bf16 bf16x8 __attribute__((ext_vector_type(8)));
typedef __bf16 bf16x4 __attribute__((ext_vector_type(4)));

#if __has_builtin(__builtin_amdgcn_exp2f)
#define EXP2F(x) __builtin_amdgcn_exp2f(x)
#else
#define EXP2F(x) exp2f(x)
#endif

#define QSCALE 0.1803368801111204f   // log2(e)/8: folds 1/sqrt(64) + base-2

// ---------------- pre-pass: K -> bf16, V -> bf16 transposed ----------------
__global__ __launch_bounds__(256)
void prep_kernel(const float* __restrict__ k, const float* __restrict__ v,
                 __bf16* __restrict__ ks, __bf16* __restrict__ vt)
{
    __shared__ __bf16 T[64][LDK];
    const int bx = blockIdx.x;
    const int tid = threadIdx.x;
    if (bx < 1536) {                       // K bf16 convert
        const int idx = (bx * 256 + tid) * 8;
        f32x4 a = *(const f32x4*)(k + idx);
        f32x4 b = *(const f32x4*)(k + idx + 4);
        bf16x8 o;
        #pragma unroll
        for (int j = 0; j < 4; ++j) { o[j] = (__bf16)a[j]; o[4 + j] = (__bf16)b[j]; }
        *(bf16x8*)(ks + idx) = o;
    } else {                               // V transpose to [bh][d][s]
        const int b2 = bx - 1536;
        const int bh = b2 >> 5;
        const int s0 = (b2 & 31) * 64;
        const int r = tid >> 2, c0 = (tid & 3) * 16;
        const float* vp = v + (size_t)bh * SEQ * DH + (size_t)(s0 + r) * DH + c0;
        __bf16 tmp[16];
        #pragma unroll
        for (int jj = 0; jj < 16; ++jj) tmp[jj] = (__bf16)vp[jj];
        *(bf16x8*)&T[r][c0]     = *(bf16x8*)&tmp[0];
        *(bf16x8*)&T[r][c0 + 8] = *(bf16x8*)&tmp[8];
        __syncthreads();
        const int d = tid >> 2, j0 = (tid & 3) * 16;
        __bf16 o[16];
        #pragma unroll
        for (int jj = 0; jj < 16; ++jj) o[jj] = T[j0 + jj][d];
        __bf16* op = vt + (size_t)bh * DH * SEQ + (size_t)d * SEQ + s0 + j0;
        *(bf16x8*)op       = *(bf16x8*)&o[0];
        *(bf16x8*)(op + 8) = *(bf16x8*)&o[8];
    }
}

// ---------------- main: BM=128, split-K(8), direct-fragment loads ----------------
__global__ __launch_bounds__(256, 4)
void fa13_kernel(const float* __restrict__ q, const __bf16* __restrict__ ks,
                 const __bf16* __restrict__ vt,
                 __bf16* __restrict__ opart, float* __restrict__ lpart,
                 float* __restrict__ out)
{
    const int bx = blockIdx.x;             // 960 = 8 XCDs x 3 headgrp x 40
    const int xcd = bx & 7;
    const int sub = bx >> 3;               // 0..119
    const int bh = (sub / 40) * 8 + xcd;   // 3 heads pinned per XCD
    const int rem = 39 - (sub % 40);       // heavy-first within XCD
    int mt2, st;
    if      (rem >= 36) { mt2 = 15; st = 36; }
    else if (rem >= 32) { mt2 = 14; st = 32; }
    else if (rem >= 28) { mt2 = 13; st = 28; }
    else if (rem >= 24) { mt2 = 12; st = 24; }
    else if (rem >= 21) { mt2 = 11; st = 21; }
    else if (rem >= 18) { mt2 = 10; st = 18; }
    else if (rem >= 15) { mt2 = 9;  st = 15; }
    else if (rem >= 12) { mt2 = 8;  st = 12; }
    else if (rem >= 10) { mt2 = 7;  st = 10; }
    else if (rem >= 8)  { mt2 = 6;  st = 8; }
    else if (rem >= 6)  { mt2 = 5;  st = 6; }
    else if (rem >= 4)  { mt2 = 4;  st = 4; }
    else                { mt2 = rem; st = rem; }
    const int chunk = rem - st;
    const int jt0 = chunk * 8;
    const int jt_end = min(jt0 + 8, 2 * mt2 + 2);
    const int q0 = mt2 * 128;

    const int tid = threadIdx.x;
    const int w = tid >> 6, lane = tid & 63;
    const int g = lane >> 4, li = lane & 15;

    __shared__ __bf16 Ps[4 * 32 * 64];     // 16 KB per-wave P tiles (only LDS)

    const __bf16* kh = ks + (size_t)bh * SEQ * DH;
    const __bf16* vh = vt + (size_t)bh * DH * SEQ;   // [d][s]

    // Q fragments: direct f32 load, scale+pack (B-operand layout for S^T)
    bf16x8 qf[2][2];
    #pragma unroll
    for (int a = 0; a < 2; ++a) {
        const float* qp = q + (size_t)bh * SEQ * DH +
                          (size_t)(q0 + w * 32 + a * 16 + li) * DH + g * 8;
        #pragma unroll
        for (int c = 0; c < 2; ++c) {
            f32x4 x0 = *(const f32x4*)(qp + c * 32);
            f32x4 x1 = *(const f32x4*)(qp + c * 32 + 4);
            #pragma unroll
            for (int j = 0; j < 4; ++j) {
                qf[a][c][j]     = (__bf16)(x0[j] * QSCALE);
                qf[a][c][4 + j] = (__bf16)(x1[j] * QSCALE);
            }
        }
    }

    bf16x8 ones;
    #pragma unroll
    for (int j = 0; j < 8; ++j) ones[j] = (__bf16)1.0f;

    f32x4 acc[2][4] = {};
    f32x4 accl[2] = {};

    for (int jt = jt0; jt < jt_end; ++jt) {
        // ---- S^T = K * Q^T, K fragments direct from global (L1/L2-hot) ----
        const __bf16* kt = kh + (size_t)jt * (BN * DH);
        float s4[2][4][4];                 // [a][t][r], kv = jt*64+t*16+g*4+r
        #pragma unroll
        for (int t = 0; t < 4; ++t) {
            f32x4 sa0 = {}, sa1 = {};
            #pragma unroll
            for (int c = 0; c < 2; ++c) {
                bf16x8 kf = *(const bf16x8*)(kt + (t * 16 + li) * DH + (c * 4 + g) * 8);
                sa0 = __builtin_amdgcn_mfma_f32_16x16x32_bf16(kf, qf[0][c], sa0, 0, 0, 0);
                sa1 = __builtin_amdgcn_mfma_f32_16x16x32_bf16(kf, qf[1][c], sa1, 0, 0, 0);
            }
            #pragma unroll
            for (int r = 0; r < 4; ++r) { s4[0][t][r] = sa0[r]; s4[1][t][r] = sa1[r]; }
        }

        if (jt >= 2 * mt2) {               // diagonal region: causal mask
            #pragma unroll
            for (int a = 0; a < 2; ++a) {
                const int qr = q0 + w * 32 + a * 16 + li;
                #pragma unroll
                for (int t = 0; t < 4; ++t) {
                    #pragma unroll
                    for (int r = 0; r < 4; ++r)
                        if (jt * 64 + t * 16 + g * 4 + r > qr) s4[a][t][r] = -1e30f;
                }
            }
        }

        // ---- p = 2^s -> packed b64 stores (4 consecutive kv per reg-quad) ----
        #pragma unroll
        for (int a = 0; a < 2; ++a) {
            const int row = a * 16 + li;
            #pragma unroll
            for (int t = 0; t < 4; ++t) {
                bf16x4 p4;
                #pragma unroll
                for (int r = 0; r < 4; ++r) p4[r] = (__bf16)EXP2F(s4[a][t][r]);
                const int pg = (t * 2 + (g >> 1)) ^ (li & 7);
                *(bf16x4*)((char*)Ps + w * 4096 + row * 128 + (pg << 4) + ((g & 1) << 3)) = p4;
            }
        }

        // ---- O += P V ; l += P * ones; V fragments direct from global ----
        #pragma unroll
        for (int c = 0; c < 2; ++c) {
            const int pgp = ((c * 4 + g) ^ (li & 7)) << 4;
            bf16x8 pf0 = *(const bf16x8*)((const char*)Ps + w * 4096 + li * 128 + pgp);
            bf16x8 pf1 = *(const bf16x8*)((const char*)Ps + w * 4096 + (16 + li) * 128 + pgp);
            accl[0] = __builtin_amdgcn_mfma_f32_16x16x32_bf16(pf0, ones, accl[0], 0, 0, 0);
            accl[1] = __builtin_amdgcn_mfma_f32_16x16x32_bf16(pf1, ones, accl[1], 0, 0, 0);
            #pragma unroll
            for (int t = 0; t < 4; ++t) {
                bf16x8 vf = *(const bf16x8*)(vh + (size_t)(t * 16 + li) * SEQ +
                                             jt * BN + (c * 4 + g) * 8);
                acc[0][t] = __builtin_amdgcn_mfma_f32_16x16x32_bf16(pf0, vf, acc[0][t], 0, 0, 0);
                acc[1][t] = __builtin_amdgcn_mfma_f32_16x16x32_bf16(pf1, vf, acc[1][t], 0, 0, 0);
            }
        }
        // no barrier: Ps is per-wave; same-wave store->load ordered by lgkmcnt
    }

    if (2 * mt2 + 2 <= 8) {
        // ---- single-chunk q-tile: normalize in-register, write out directly
        float* oh = out + (size_t)bh * SEQ * DH;
        #pragma unroll
        for (int a = 0; a < 2; ++a) {
            #pragma unroll
            for (int r = 0; r < 4; ++r) {
                const int row = q0 + w * 32 + a * 16 + g * 4 + r;
                const float inv = 1.0f / accl[a][r];
                float* op = oh + (size_t)row * DH + li;
                #pragma unroll
                for (int t = 0; t < 4; ++t) op[t * 16] = acc[a][t][r] * inv;
            }
        }
    } else {
        // ---- partials out (O in bf16; l in f32) ----
        const int slot = (bh * 16 + mt2) * 4 + chunk;
        __bf16* po = opart + (size_t)slot * 8192;
        #pragma unroll
        for (int a = 0; a < 2; ++a) {
            #pragma unroll
            for (int r = 0; r < 4; ++r) {
                const int row = w * 32 + a * 16 + g * 4 + r;
                __bf16* op = po + row * 64 + li;
                #pragma unroll
                for (int t = 0; t < 4; ++t) op[t * 16] = (__bf16)acc[a][t][r];
                if (li == 0) lpart[(size_t)slot * 128 + row] = accl[a][r];
            }
        }
    }
}

// ---------------- reduce: sum bf16 chunks, normalize (mt2 >= 4 only) ----------------
__global__ __launch_bounds__(256)
void fa_reduce(const __bf16* __restrict__ opart, const float* __restrict__ lpart,
               float* __restrict__ out)
{
    const int bx = blockIdx.x;             // 288 = 8 XCDs x 3 headgrp x 12
    const int xcd = bx & 7;
    const int r2 = bx >> 3;                // 0..35
    const int bh = (r2 / 12) * 8 + xcd;    // co-locate with producer XCD
    const int mt2 = 4 + (r2 % 12);
    const int nc = (mt2 >> 2) + 1;         // ceil((2*mt2+2)/8)
    const int base = (bh * 16 + mt2) * 4;
    const int tid = threadIdx.x;
    #pragma unroll
    for (int rnd = 0; rnd < 8; ++rnd) {
        const int flat = rnd * 1024 + tid * 4;
        const int row = flat >> 6;
        float o0 = 0, o1 = 0, o2 = 0, o3 = 0, l = 0;
        for (int c = 0; c < nc; ++c) {
            bf16x4 ov = *(const bf16x4*)(opart + (size_t)(base + c) * 8192 + flat);
            o0 += (float)ov[0]; o1 += (float)ov[1]; o2 += (float)ov[2]; o3 += (float)ov[3];
            l += lpart[(size_t)(base + c) * 128 + row];
        }
        const float inv = 1.0f / l;
        f32x4 res = { o0 * inv, o1 * inv, o2 * inv, o3 * inv };
        *(f32x4*)(out + (size_t)bh * SEQ * DH + (size_t)mt2 * 8192 + flat) = res;
    }
}

// ---------------- fallback: R1 self-contained kernel ----------------
__global__ __launch_bounds__(256, 2)
void fa_causal_kernel(const float* __restrict__ q, const float* __restrict__ k,
                      const float* __restrict__ v, float* __restrict__ out)
{
    const int mt = 31 - (blockIdx.x & 31);
    const int bh = blockIdx.x >> 5;
    const int tid = threadIdx.x;
    const int w = tid >> 6, lane = tid & 63;
    const int g = lane >> 4, li = lane & 15;
    const int m0 = mt * 64;
    __shared__ __bf16 KsF[BN][LDK];
    __shared__ __bf16 VsF[DH][LDK];
    __shared__ __bf16 PsF[4][16][LDK];
    const size_t head_off = (size_t)bh * SEQ * DH;
    const float* qh = q + head_off;
    const float* kh = k + head_off;
    const float* vh = v + head_off;
    float* oh = out + head_off;
    const int qrow = m0 + w * 16 + li;
    bf16x8 qf[2];
    {
        const float* qp = qh + (size_t)qrow * DH + g * 8;
        #pragma unroll
        for (int c = 0; c < 2; ++c) {
            const float* p = qp + c * 32;
            #pragma unroll
            for (int jj = 0; jj < 8; ++jj) qf[c][jj] = (__bf16)p[jj];
        }
    }
    f32x4 acc[4] = {};
    float mrow[4], lrow[4];
    #pragma unroll
    for (int r = 0; r < 4; ++r) { mrow[r] = -1e30f; lrow[r] = 0.0f; }
    const float scale = 0.125f;
    const int srow = tid >> 2, scol = (tid & 3) * 16;
    for (int jt = 0; jt <= mt; ++jt) {
        const int kv0 = jt * BN;
        __syncthreads();
        {
            const float* kp = kh + (size_t)(kv0 + srow) * DH + scol;
            __bf16 tmp[16];
            #pragma unroll
            for (int jj = 0; jj < 16; ++jj) tmp[jj] = (__bf16)kp[jj];
            *(bf16x8*)&KsF[srow][scol]     = *(bf16x8*)&tmp[0];
            *(bf16x8*)&KsF[srow][scol + 8] = *(bf16x8*)&tmp[8];
            const float* vp = vh + (size_t)(kv0 + srow) * DH + scol;
            #pragma unroll
            for (int jj = 0; jj < 16; ++jj) VsF[scol + jj][srow] = (__bf16)vp[jj];
        }
        __syncthreads();
        float s4[4][4];
        #pragma unroll
        for (int t = 0; t < 4; ++t) {
            f32x4 sa = {};
            #pragma unroll
            for (int c = 0; c < 2; ++c) {
                bf16x8 kfr = *(const bf16x8*)&KsF[t * 16 + li][c * 32 + g * 8];
                sa = __builtin_amdgcn_mfma_f32_16x16x32_bf16(qf[c], kfr, sa, 0, 0, 0);
            }
            #pragma unroll
            for (int r = 0; r < 4; ++r) s4[t][r] = sa[r] * scale;
        }
        if (jt == mt) {
            #pragma unroll
            for (int t = 0; t < 4; ++t) {
                const int col = kv0 + t * 16 + li;
                #pragma unroll
                for (int r = 0; r < 4; ++r)
                    if (col > m0 + w * 16 + g * 4 + r) s4[t][r] = -1e30f;
            }
        }
        #pragma unroll
        for (int r = 0; r < 4; ++r) {
            float mx = fmaxf(fmaxf(s4[0][r], s4[1][r]), fmaxf(s4[2][r], s4[3][r]));
            #pragma unroll
            for (int off = 1; off < 16; off <<= 1)
                mx = fmaxf(mx, __shfl_xor(mx, off, 64));
            const float mnew = fmaxf(mrow[r], mx);
            const float alpha = __expf(mrow[r] - mnew);
            mrow[r] = mnew;
            float ps = 0.0f;
            #pragma unroll
            for (int t = 0; t < 4; ++t) {
                const float p = __expf(s4[t][r] - mnew);
                s4[t][r] = p;
                ps += p;
            }
            #pragma unroll
            for (int off = 1; off < 16; off <<= 1)
                ps += __shfl_xor(ps, off, 64);
            lrow[r] = lrow[r] * alpha + ps;
            #pragma unroll
            for (int t = 0; t < 4; ++t) acc[t][r] *= alpha;
        }
        #pragma unroll
        for (int t = 0; t < 4; ++t)
            #pragma unroll
            for (int r = 0; r < 4; ++r)
                PsF[w][g * 4 + r][t * 16 + li] = (__bf16)s4[t][r];
        __syncthreads();
        #pragma unroll
        for (int c = 0; c < 2; ++c) {
            bf16x8 pf = *(const bf16x8*)&PsF[w][li][c * 32 + g * 8];
            #pragma unroll
            for (int t = 0; t < 4; ++t) {
                bf16x8 vfr = *(const bf16x8*)&VsF[t * 16 + li][c * 32 + g * 8];
                acc[t] = __builtin_amdgcn_mfma_f32_16x16x32_bf16(pf, vfr, acc[t], 0, 0, 0);
            }
        }
    }
    #pragma unroll
    for (int r = 0; r < 4; ++r) {
        const int row = m0 + w * 16 + g * 4 + r;
        const float inv = 1.0f / lrow[r];
        float* op = oh + (size_t)row * DH + li;
        #pragma unroll
        for (int t = 0; t < 4; ++t) op[t * 16] = acc[t][r] * inv;
    }
}

extern "C" void kernel_launch(void* const* d_in, const int* in_sizes, int n_in,
                              void* d_out, int out_size, void* d_ws, size_t ws_size,
                              hipStream_t stream) {
    (void)in_sizes; (void)n_in; (void)out_size;
    const float* q = (const float*)d_in[0];
    const float* k = (const float*)d_in[1];
    const float* v = (const float*)d_in[2];
    float* out = (float*)d_out;

    if (ws_size >= WS_FA11) {
        __bf16* ks = (__bf16*)d_ws;
        __bf16* vt = ks + ELEMS_PER_TENSOR;
        __bf16* opart = (__bf16*)((char*)d_ws + WS_KV);
        float* lpart = (float*)((char*)d_ws + WS_KV + (size_t)NSLOT * 8192 * 2);
        prep_kernel<<<dim3(1536 + 768), dim3(256), 0, stream>>>(k, v, ks, vt);
        fa13_kernel<<<dim3(960), dim3(256), 0, stream>>>(q, ks, vt, opart, lpart, out);
        fa_reduce<<<dim3(288), dim3(256), 0, stream>>>(opart, lpart, out);
    } else {
        fa_causal_kernel<<<dim3(NHEADS * 32), dim3(256), 0, stream>>>(q, k, v, out);
    }
}

// Round 4
// 137.894 us; speedup vs baseline: 2.0018x; 1.2152x over previous
//
#include <hip/hip_runtime.h>
#include <hip/hip_bf16.h>

// Causal attention B=2,H=12,S=2048,D=64 fp32 in/out.
// R15 = R14 resubmitted verbatim (R14 bench died with "container failed
// twice" = infra error; kernel has no cross-block sync / no spin / no fences
// so it cannot hang -> re-run the same experiment, don't mutate two vars).
// R14 = R11 pipeline (best: 131.8us total, fa ~40us) with prep_kernel FOLDED IN
// (2 dispatches: fa14 + reduce). R13 lesson: direct-global MFMA operands are
// latency-bound (68us, MfmaUtil 8%) -> the staged dbuf pipeline is the latency
// hider, keep it. R12 lesson: no device-scope sync in-kernel.
//  - K staged from ORIGINAL f32 k (cvt at commit), R11-identical LDS layout.
//  - V staged from ORIGINAL f32 v into a B-operand-native LDS layout:
//    elem (k,d) at byte ((p*2+c)*4+g)*256 + ((dd^h)<<4) + j*2, with p=d>>4,
//    dd=d&15, c=k>>5, g=(k>>3)&3, j=k&7, h=g|(p<<2). PV's vf is then ONE
//    contiguous b128 read at grp*256 + ((li^h)<<4) (conflict-free: 8 lanes
//    per 4-bank group = b128 minimum). Staging writes = 16 ds_write_b16 at
//    16B stride, XOR-spread across all 32 banks (same bank-pass count as
//    2x b128). k-permutation is internal to Vs; P path untouched.
//  - Kills: prep dispatch (~8us) + 1 dispatch boundary (~10us) + 19MB of
//    bf16 ks/vt bounce traffic. Costs: f32 staging loads (2x bytes, L2-res:
//    3MB/XCD) + ~32 cvt VALU/thread/tile.
// Carried: split-K chunks of 8 k-tiles (960 blocks), Q-direct load, single-
// chunk q-tiles (mt2<=3) normalize in-register, XCD swizzle (3 heads/XCD),
// double-buffered K/V + 1 barrier/iter, bf16 partial O + f32 l, BM=128,
// S^T=K*Q^T, static-max base-2 softmax, XOR-swizzled packed Ps.

#define SEQ 2048
#define DH 64
#define NHEADS 24
#define BN 64
#define LDK 72
#define NSLOT (NHEADS * 16 * 4)                       // 1536
#define WS_FA14  ((size_t)NSLOT * 8192 * 2 + (size_t)NSLOT * 128 * 4)

typedef float f32x4 __attribute__((ext_vector_type(4)));
typedef __bf16 bf16x8 __attribute__((ext_vector_type(8)));
typedef __bf16 bf16x4 __attribute__((ext_vector_type(4)));

#if __has_builtin(__builtin_amdgcn_exp2f)
#define EXP2F(x) __builtin_amdgcn_exp2f(x)
#else
#define EXP2F(x) exp2f(x)
#endif

#define QSCALE 0.1803368801111204f   // log2(e)/8: folds 1/sqrt(64) + base-2

// ---------------- main: BM=128, split-K(8), dbuf, fused K/V convert ----------------
__global__ __launch_bounds__(256, 3)
void fa14_kernel(const float* __restrict__ q, const float* __restrict__ k,
                 const float* __restrict__ v,
                 __bf16* __restrict__ opart, float* __restrict__ lpart,
                 float* __restrict__ out)
{
    const int bx = blockIdx.x;             // 960 = 8 XCDs x 3 headgrp x 40
    const int xcd = bx & 7;
    const int sub = bx >> 3;               // 0..119
    const int bh = (sub / 40) * 8 + xcd;   // 3 heads pinned per XCD
    const int rem = 39 - (sub % 40);       // heavy-first within XCD
    int mt2, st;
    if      (rem >= 36) { mt2 = 15; st = 36; }
    else if (rem >= 32) { mt2 = 14; st = 32; }
    else if (rem >= 28) { mt2 = 13; st = 28; }
    else if (rem >= 24) { mt2 = 12; st = 24; }
    else if (rem >= 21) { mt2 = 11; st = 21; }
    else if (rem >= 18) { mt2 = 10; st = 18; }
    else if (rem >= 15) { mt2 = 9;  st = 15; }
    else if (rem >= 12) { mt2 = 8;  st = 12; }
    else if (rem >= 10) { mt2 = 7;  st = 10; }
    else if (rem >= 8)  { mt2 = 6;  st = 8; }
    else if (rem >= 6)  { mt2 = 5;  st = 6; }
    else if (rem >= 4)  { mt2 = 4;  st = 4; }
    else                { mt2 = rem; st = rem; }
    const int chunk = rem - st;
    const int jt0 = chunk * 8;
    const int jt_end = min(jt0 + 8, 2 * mt2 + 2);
    const int q0 = mt2 * 128;

    const int tid = threadIdx.x;
    const int w = tid >> 6, lane = tid & 63;
    const int g = lane >> 4, li = lane & 15;

    __shared__ __bf16 Ks[2][4096];         // 16 KB double-buffered
    __shared__ __bf16 Vs[2][4096];         // 16 KB, B-operand-native layout
    __shared__ __bf16 Ps[4 * 32 * 64];     // 16 KB per-wave P tiles

    const float* kh = k + (size_t)bh * SEQ * DH;
    const float* vh = v + (size_t)bh * SEQ * DH;

    // Q fragments: direct f32 load, scale+pack (B-operand layout for S^T)
    bf16x8 qf[2][2];
    #pragma unroll
    for (int a = 0; a < 2; ++a) {
        const float* qp = q + (size_t)bh * SEQ * DH +
                          (size_t)(q0 + w * 32 + a * 16 + li) * DH + g * 8;
        #pragma unroll
        for (int c = 0; c < 2; ++c) {
            f32x4 x0 = *(const f32x4*)(qp + c * 32);
            f32x4 x1 = *(const f32x4*)(qp + c * 32 + 4);
            #pragma unroll
            for (int j = 0; j < 4; ++j) {
                qf[a][c][j]     = (__bf16)(x0[j] * QSCALE);
                qf[a][c][4 + j] = (__bf16)(x1[j] * QSCALE);
            }
        }
    }

    bf16x8 ones;
    #pragma unroll
    for (int j = 0; j < 8; ++j) ones[j] = (__bf16)1.0f;

    f32x4 acc[2][4] = {};
    f32x4 accl[2] = {};

    // K staging map (R11-identical write pattern): rows srow0, srow0+32
    const int srow0 = tid >> 3;
    const int sg    = tid & 7;
    const int klg   = sg ^ (srow0 & 7);    // (srow0+32)&7 == srow0&7

    // V staging map: row vrow, d-panel vp (16 cols)
    const int vrow = tid >> 2;
    const int vp   = tid & 3;
    const int vc = vrow >> 5, vg = (vrow >> 3) & 3, vj = vrow & 7;
    const int vwbase = (((vp * 2 + vc) * 4 + vg) << 8) |
                       ((vg | (vp << 2)) << 4) | (vj << 1);

    f32x4 ka[2][2], va[4];
    auto issueKV = [&](int jt) {
        const float* kp = kh + (size_t)(jt * BN + srow0) * DH + klg * 8;
        ka[0][0] = *(const f32x4*)kp;
        ka[0][1] = *(const f32x4*)(kp + 4);
        kp += 32 * DH;
        ka[1][0] = *(const f32x4*)kp;
        ka[1][1] = *(const f32x4*)(kp + 4);
        const float* vpx = vh + (size_t)(jt * BN + vrow) * DH + vp * 16;
        #pragma unroll
        for (int jj = 0; jj < 4; ++jj) va[jj] = *(const f32x4*)(vpx + jj * 4);
    };
    auto commitKV = [&](int b) {
        #pragma unroll
        for (int s = 0; s < 2; ++s) {
            bf16x8 o;
            #pragma unroll
            for (int jj = 0; jj < 4; ++jj) {
                o[jj]     = (__bf16)ka[s][0][jj];
                o[4 + jj] = (__bf16)ka[s][1][jj];
            }
            *(bf16x8*)((char*)Ks[b] + s * 4096 + tid * 16) = o;
        }
        __bf16 vv[16];
        #pragma unroll
        for (int jj = 0; jj < 16; ++jj) vv[jj] = (__bf16)va[jj >> 2][jj & 3];
        #pragma unroll
        for (int dd = 0; dd < 16; ++dd)
            *(__bf16*)((char*)Vs[b] + (vwbase ^ (dd << 4))) = vv[dd];
    };

    // ---- prologue: tile jt0 -> buf0; issue loads for jt0+1 ----
    issueKV(jt0);
    commitKV(0);
    if (jt0 + 1 < jt_end) issueKV(jt0 + 1);
    __syncthreads();

    int buf = 0;
    for (int jt = jt0; jt < jt_end; ++jt) {
        // commit tile jt+1 (regs loaded a full iteration ago) into buf^1
        if (jt + 1 < jt_end) commitKV(buf ^ 1);
        // issue loads for tile jt+2
        if (jt + 2 < jt_end) issueKV(jt + 2);

        // ---- S^T = K * Q^T from buf ----
        const char* Kb = (const char*)Ks[buf];
        float s4[2][4][4];                 // [a][t][r], kv = jt*64+t*16+g*4+r
        #pragma unroll
        for (int t = 0; t < 4; ++t) {
            f32x4 sa0 = {}, sa1 = {};
            #pragma unroll
            for (int c = 0; c < 2; ++c) {
                bf16x8 kf = *(const bf16x8*)(Kb +
                    (t * 16 + li) * 128 + (((c * 4 + g) ^ (li & 7)) << 4));
                sa0 = __builtin_amdgcn_mfma_f32_16x16x32_bf16(kf, qf[0][c], sa0, 0, 0, 0);
                sa1 = __builtin_amdgcn_mfma_f32_16x16x32_bf16(kf, qf[1][c], sa1, 0, 0, 0);
            }
            #pragma unroll
            for (int r = 0; r < 4; ++r) { s4[0][t][r] = sa0[r]; s4[1][t][r] = sa1[r]; }
        }

        if (jt >= 2 * mt2) {               // diagonal region: causal mask
            #pragma unroll
            for (int a = 0; a < 2; ++a) {
                const int qr = q0 + w * 32 + a * 16 + li;
                #pragma unroll
                for (int t = 0; t < 4; ++t) {
                    #pragma unroll
                    for (int r = 0; r < 4; ++r)
                        if (jt * 64 + t * 16 + g * 4 + r > qr) s4[a][t][r] = -1e30f;
                }
            }
        }

        // ---- p = 2^s -> packed b64 stores (4 consecutive kv per reg-quad) ----
        #pragma unroll
        for (int a = 0; a < 2; ++a) {
            const int row = a * 16 + li;
            #pragma unroll
            for (int t = 0; t < 4; ++t) {
                bf16x4 p4;
                #pragma unroll
                for (int r = 0; r < 4; ++r) p4[r] = (__bf16)EXP2F(s4[a][t][r]);
                const int pg = (t * 2 + (g >> 1)) ^ (li & 7);
                *(bf16x4*)((char*)Ps + w * 4096 + row * 128 + (pg << 4) + ((g & 1) << 3)) = p4;
            }
        }

        // ---- O += P V ; l += P * ones; V fragments: single b128 reads ----
        #pragma unroll
        for (int c = 0; c < 2; ++c) {
            const int pgp = ((c * 4 + g) ^ (li & 7)) << 4;
            bf16x8 pf0 = *(const bf16x8*)((const char*)Ps + w * 4096 + li * 128 + pgp);
            bf16x8 pf1 = *(const bf16x8*)((const char*)Ps + w * 4096 + (16 + li) * 128 + pgp);
            accl[0] = __builtin_amdgcn_mfma_f32_16x16x32_bf16(pf0, ones, accl[0], 0, 0, 0);
            accl[1] = __builtin_amdgcn_mfma_f32_16x16x32_bf16(pf1, ones, accl[1], 0, 0, 0);
            #pragma unroll
            for (int t = 0; t < 4; ++t) {
                bf16x8 vf = *(const bf16x8*)((const char*)Vs[buf] +
                    ((((t * 2 + c) * 4 + g) << 8) | ((li ^ (g | (t << 2))) << 4)));
                acc[0][t] = __builtin_amdgcn_mfma_f32_16x16x32_bf16(pf0, vf, acc[0][t], 0, 0, 0);
                acc[1][t] = __builtin_amdgcn_mfma_f32_16x16x32_bf16(pf1, vf, acc[1][t], 0, 0, 0);
            }
        }

        if (jt + 1 < jt_end) __syncthreads();   // readers of buf done; buf^1 ready
        buf ^= 1;
    }

    if (2 * mt2 + 2 <= 8) {
        // ---- single-chunk q-tile: normalize in-register, write out directly
        float* oh = out + (size_t)bh * SEQ * DH;
        #pragma unroll
        for (int a = 0; a < 2; ++a) {
            #pragma unroll
            for (int r = 0; r < 4; ++r) {
                const int row = q0 + w * 32 + a * 16 + g * 4 + r;
                const float inv = 1.0f / accl[a][r];
                float* op = oh + (size_t)row * DH + li;
                #pragma unroll
                for (int t = 0; t < 4; ++t) op[t * 16] = acc[a][t][r] * inv;
            }
        }
    } else {
        // ---- partials out (O in bf16; l in f32) ----
        const int slot = (bh * 16 + mt2) * 4 + chunk;
        __bf16* po = opart + (size_t)slot * 8192;
        #pragma unroll
        for (int a = 0; a < 2; ++a) {
            #pragma unroll
            for (int r = 0; r < 4; ++r) {
                const int row = w * 32 + a * 16 + g * 4 + r;
                __bf16* op = po + row * 64 + li;
                #pragma unroll
                for (int t = 0; t < 4; ++t) op[t * 16] = (__bf16)acc[a][t][r];
                if (li == 0) lpart[(size_t)slot * 128 + row] = accl[a][r];
            }
        }
    }
}

// ---------------- reduce: sum bf16 chunks, normalize (mt2 >= 4 only) ----------------
__global__ __launch_bounds__(256)
void fa_reduce(const __bf16* __restrict__ opart, const float* __restrict__ lpart,
               float* __restrict__ out)
{
    const int bx = blockIdx.x;             // 288 = 8 XCDs x 3 headgrp x 12
    const int xcd = bx & 7;
    const int r2 = bx >> 3;                // 0..35
    const int bh = (r2 / 12) * 8 + xcd;    // co-locate with producer XCD
    const int mt2 = 4 + (r2 % 12);
    const int nc = (mt2 >> 2) + 1;         // ceil((2*mt2+2)/8)
    const int base = (bh * 16 + mt2) * 4;
    const int tid = threadIdx.x;
    #pragma unroll
    for (int rnd = 0; rnd < 8; ++rnd) {
        const int flat = rnd * 1024 + tid * 4;
        const int row = flat >> 6;
        float o0 = 0, o1 = 0, o2 = 0, o3 = 0, l = 0;
        for (int c = 0; c < nc; ++c) {
            bf16x4 ov = *(const bf16x4*)(opart + (size_t)(base + c) * 8192 + flat);
            o0 += (float)ov[0]; o1 += (float)ov[1]; o2 += (float)ov[2]; o3 += (float)ov[3];
            l += lpart[(size_t)(base + c) * 128 + row];
        }
        const float inv = 1.0f / l;
        f32x4 res = { o0 * inv, o1 * inv, o2 * inv, o3 * inv };
        *(f32x4*)(out + (size_t)bh * SEQ * DH + (size_t)mt2 * 8192 + flat) = res;
    }
}

// ---------------- fallback: R1 self-contained kernel ----------------
__global__ __launch_bounds__(256, 2)
void fa_causal_kernel(const float* __restrict__ q, const float* __restrict__ k,
                      const float* __restrict__ v, float* __restrict__ out)
{
    const int mt = 31 - (blockIdx.x & 31);
    const int bh = blockIdx.x >> 5;
    const int tid = threadIdx.x;
    const int w = tid >> 6, lane = tid & 63;
    const int g = lane >> 4, li = lane & 15;
    const int m0 = mt * 64;
    __shared__ __bf16 KsF[BN][LDK];
    __shared__ __bf16 VsF[DH][LDK];
    __shared__ __bf16 PsF[4][16][LDK];
    const size_t head_off = (size_t)bh * SEQ * DH;
    const float* qh = q + head_off;
    const float* kh = k + head_off;
    const float* vh = v + head_off;
    float* oh = out + head_off;
    const int qrow = m0 + w * 16 + li;
    bf16x8 qf[2];
    {
        const float* qp = qh + (size_t)qrow * DH + g * 8;
        #pragma unroll
        for (int c = 0; c < 2; ++c) {
            const float* p = qp + c * 32;
            #pragma unroll
            for (int jj = 0; jj < 8; ++jj) qf[c][jj] = (__bf16)p[jj];
        }
    }
    f32x4 acc[4] = {};
    float mrow[4], lrow[4];
    #pragma unroll
    for (int r = 0; r < 4; ++r) { mrow[r] = -1e30f; lrow[r] = 0.0f; }
    const float scale = 0.125f;
    const int srow = tid >> 2, scol = (tid & 3) * 16;
    for (int jt = 0; jt <= mt; ++jt) {
        const int kv0 = jt * BN;
        __syncthreads();
        {
            const float* kp = kh + (size_t)(kv0 + srow) * DH + scol;
            __bf16 tmp[16];
            #pragma unroll
            for (int jj = 0; jj < 16; ++jj) tmp[jj] = (__bf16)kp[jj];
            *(bf16x8*)&KsF[srow][scol]     = *(bf16x8*)&tmp[0];
            *(bf16x8*)&KsF[srow][scol + 8] = *(bf16x8*)&tmp[8];
            const float* vp = vh + (size_t)(kv0 + srow) * DH + scol;
            #pragma unroll
            for (int jj = 0; jj < 16; ++jj) VsF[scol + jj][srow] = (__bf16)vp[jj];
        }
        __syncthreads();
        float s4[4][4];
        #pragma unroll
        for (int t = 0; t < 4; ++t) {
            f32x4 sa = {};
            #pragma unroll
            for (int c = 0; c < 2; ++c) {
                bf16x8 kfr = *(const bf16x8*)&KsF[t * 16 + li][c * 32 + g * 8];
                sa = __builtin_amdgcn_mfma_f32_16x16x32_bf16(qf[c], kfr, sa, 0, 0, 0);
            }
            #pragma unroll
            for (int r = 0; r < 4; ++r) s4[t][r] = sa[r] * scale;
        }
        if (jt == mt) {
            #pragma unroll
            for (int t = 0; t < 4; ++t) {
                const int col = kv0 + t * 16 + li;
                #pragma unroll
                for (int r = 0; r < 4; ++r)
                    if (col > m0 + w * 16 + g * 4 + r) s4[t][r] = -1e30f;
            }
        }
        #pragma unroll
        for (int r = 0; r < 4; ++r) {
            float mx = fmaxf(fmaxf(s4[0][r], s4[1][r]), fmaxf(s4[2][r], s4[3][r]));
            #pragma unroll
            for (int off = 1; off < 16; off <<= 1)
                mx = fmaxf(mx, __shfl_xor(mx, off, 64));
            const float mnew = fmaxf(mrow[r], mx);
            const float alpha = __expf(mrow[r] - mnew);
            mrow[r] = mnew;
            float ps = 0.0f;
            #pragma unroll
            for (int t = 0; t < 4; ++t) {
                const float p = __expf(s4[t][r] - mnew);
                s4[t][r] = p;
                ps += p;
            }
            #pragma unroll
            for (int off = 1; off < 16; off <<= 1)
                ps += __shfl_xor(ps, off, 64);
            lrow[r] = lrow[r] * alpha + ps;
            #pragma unroll
            for (int t = 0; t < 4; ++t) acc[t][r] *= alpha;
        }
        #pragma unroll
        for (int t = 0; t < 4; ++t)
            #pragma unroll
            for (int r = 0; r < 4; ++r)
                PsF[w][g * 4 + r][t * 16 + li] = (__bf16)s4[t][r];
        __syncthreads();
        #pragma unroll
        for (int c = 0; c < 2; ++c) {
            bf16x8 pf = *(const bf16x8*)&PsF[w][li][c * 32 + g * 8];
            #pragma unroll
            for (int t = 0; t < 4; ++t) {
                bf16x8 vfr = *(const bf16x8*)&VsF[t * 16 + li][c * 32 + g * 8];
                acc[t] = __builtin_amdgcn_mfma_f32_16x16x32_bf16(pf, vfr, acc[t], 0, 0, 0);
            }
        }
    }
    #pragma unroll
    for (int r = 0; r < 4; ++r) {
        const int row = m0 + w * 16 + g * 4 + r;
        const float inv = 1.0f / lrow[r];
        float* op = oh + (size_t)row * DH + li;
        #pragma unroll
        for (int t = 0; t < 4; ++t) op[t * 16] = acc[t][r] * inv;
    }
}

extern "C" void kernel_launch(void* const* d_in, const int* in_sizes, int n_in,
                              void* d_out, int out_size, void* d_ws, size_t ws_size,
                              hipStream_t stream) {
    (void)in_sizes; (void)n_in; (void)out_size;
    const float* q = (const float*)d_in[0];
    const float* k = (const float*)d_in[1];
    const float* v = (const float*)d_in[2];
    float* out = (float*)d_out;

    if (ws_size >= WS_FA14) {
        __bf16* opart = (__bf16*)d_ws;
        float* lpart = (float*)((char*)d_ws + (size_t)NSLOT * 8192 * 2);
        fa14_kernel<<<dim3(960), dim3(256), 0, stream>>>(q, k, v, opart, lpart, out);
        fa_reduce<<<dim3(288), dim3(256), 0, stream>>>(opart, lpart, out);
    } else {
        fa_causal_kernel<<<dim3(NHEADS * 32), dim3(256), 0, stream>>>(q, k, v, out);
    }
}

// Round 5
// 126.647 us; speedup vs baseline: 2.1796x; 1.0888x over previous
//
#include <hip/hip_runtime.h>
#include <hip/hip_bf16.h>

// Causal attention B=2,H=12,S=2048,D=64 fp32 in/out.
// R16 = R15 (fused prep, 2 dispatches; total 137.9, fa14 47.3us) with the two
// PROFILED regressions fixed:
//  - V staging: 16x ds_write_b16 -> 4x ds_write_b64. Staging thread owns a
//    4x4 (k x d) sub-block: kb=(tid>>4)*4, dr=(tid&15)*4; loads 4 row-f32x4
//    (each wave-instr = 4 full 256B rows, perfectly coalesced), in-register
//    4x4 transpose, one bf16x4 write per d. Address algebra verified against
//    the unchanged read side (elem kv=37,d=21 -> byte 3098 both sides).
//    R15 counters showed the b16 path DOUBLED bank conflicts (835K->1671K)
//    and doubled VALUBusy (addressing) -> this is the measured fix.
//  - s_setprio(1)/(0) around QK and PV MFMA clusters (T5: helps when waves
//    have phase diversity; here 1 barrier/iter + 3 blocks/CU).
// Carried from R15/R11: K staged f32->bf16 at commit (R11 LDS layout), split-K
// chunks of 8 k-tiles (960 blocks), Q-direct load, single-chunk q-tiles
// normalize in-register, XCD swizzle (3 heads/XCD), dbuf K/V + 1 barrier/iter,
// bf16 partial O + f32 l, BM=128, S^T=K*Q^T, static-max base-2 softmax,
// XOR-swizzled packed Ps. R13 lesson: keep the LDS staging pipeline (latency
// hider). R12 lesson: no device-scope sync in-kernel.

#define SEQ 2048
#define DH 64
#define NHEADS 24
#define BN 64
#define LDK 72
#define NSLOT (NHEADS * 16 * 4)                       // 1536
#define WS_FA14  ((size_t)NSLOT * 8192 * 2 + (size_t)NSLOT * 128 * 4)

typedef float f32x4 __attribute__((ext_vector_type(4)));
typedef __bf16 bf16x8 __attribute__((ext_vector_type(8)));
typedef __bf16 bf16x4 __attribute__((ext_vector_type(4)));

#if __has_builtin(__builtin_amdgcn_exp2f)
#define EXP2F(x) __builtin_amdgcn_exp2f(x)
#else
#define EXP2F(x) exp2f(x)
#endif

#define QSCALE 0.1803368801111204f   // log2(e)/8: folds 1/sqrt(64) + base-2

// ---------------- main: BM=128, split-K(8), dbuf, fused K/V convert ----------------
__global__ __launch_bounds__(256, 3)
void fa16_kernel(const float* __restrict__ q, const float* __restrict__ k,
                 const float* __restrict__ v,
                 __bf16* __restrict__ opart, float* __restrict__ lpart,
                 float* __restrict__ out)
{
    const int bx = blockIdx.x;             // 960 = 8 XCDs x 3 headgrp x 40
    const int xcd = bx & 7;
    const int sub = bx >> 3;               // 0..119
    const int bh = (sub / 40) * 8 + xcd;   // 3 heads pinned per XCD
    const int rem = 39 - (sub % 40);       // heavy-first within XCD
    int mt2, st;
    if      (rem >= 36) { mt2 = 15; st = 36; }
    else if (rem >= 32) { mt2 = 14; st = 32; }
    else if (rem >= 28) { mt2 = 13; st = 28; }
    else if (rem >= 24) { mt2 = 12; st = 24; }
    else if (rem >= 21) { mt2 = 11; st = 21; }
    else if (rem >= 18) { mt2 = 10; st = 18; }
    else if (rem >= 15) { mt2 = 9;  st = 15; }
    else if (rem >= 12) { mt2 = 8;  st = 12; }
    else if (rem >= 10) { mt2 = 7;  st = 10; }
    else if (rem >= 8)  { mt2 = 6;  st = 8; }
    else if (rem >= 6)  { mt2 = 5;  st = 6; }
    else if (rem >= 4)  { mt2 = 4;  st = 4; }
    else                { mt2 = rem; st = rem; }
    const int chunk = rem - st;
    const int jt0 = chunk * 8;
    const int jt_end = min(jt0 + 8, 2 * mt2 + 2);
    const int q0 = mt2 * 128;

    const int tid = threadIdx.x;
    const int w = tid >> 6, lane = tid & 63;
    const int g = lane >> 4, li = lane & 15;

    __shared__ __bf16 Ks[2][4096];         // 16 KB double-buffered
    __shared__ __bf16 Vs[2][4096];         // 16 KB, B-operand-native layout
    __shared__ __bf16 Ps[4 * 32 * 64];     // 16 KB per-wave P tiles

    const float* kh = k + (size_t)bh * SEQ * DH;
    const float* vh = v + (size_t)bh * SEQ * DH;

    // Q fragments: direct f32 load, scale+pack (B-operand layout for S^T)
    bf16x8 qf[2][2];
    #pragma unroll
    for (int a = 0; a < 2; ++a) {
        const float* qp = q + (size_t)bh * SEQ * DH +
                          (size_t)(q0 + w * 32 + a * 16 + li) * DH + g * 8;
        #pragma unroll
        for (int c = 0; c < 2; ++c) {
            f32x4 x0 = *(const f32x4*)(qp + c * 32);
            f32x4 x1 = *(const f32x4*)(qp + c * 32 + 4);
            #pragma unroll
            for (int j = 0; j < 4; ++j) {
                qf[a][c][j]     = (__bf16)(x0[j] * QSCALE);
                qf[a][c][4 + j] = (__bf16)(x1[j] * QSCALE);
            }
        }
    }

    bf16x8 ones;
    #pragma unroll
    for (int j = 0; j < 8; ++j) ones[j] = (__bf16)1.0f;

    f32x4 acc[2][4] = {};
    f32x4 accl[2] = {};

    // K staging map (R11-identical write pattern): rows srow0, srow0+32
    const int srow0 = tid >> 3;
    const int sg    = tid & 7;
    const int klg   = sg ^ (srow0 & 7);    // (srow0+32)&7 == srow0&7

    // V staging map: thread owns 4x4 (k x d) sub-block, writes 4x b64.
    // kb = (tid>>4)*4 (4 k-rows), dr = (tid&15)*4 (4 d's).
    // addr(dd) = vwb ^ (dd<<4); vwb = G<<8 | S32<<6 | g<<4 | jh<<3,
    // G=(p*2+c)*4+gv, S32=((dr>>2)&3)^p, p=dr>>4, c=kb>>5, gv=(kb>>3)&3,
    // jh=(kb>>2)&1. Verified vs read map: slot = (d&15)^(gv|(p<<2)).
    const int kb = (tid >> 4) << 2;
    const int dr = (tid & 15) << 2;
    const int vc  = kb >> 5;
    const int vg  = (kb >> 3) & 3;
    const int vjh = (kb >> 2) & 1;
    const int vpp = dr >> 4;
    const int vS32 = ((dr >> 2) & 3) ^ vpp;
    const int vwb = (((vpp * 2 + vc) * 4 + vg) << 8) | (vS32 << 6) |
                    (vg << 4) | (vjh << 3);

    f32x4 ka[2][2], va[4];
    auto issueKV = [&](int jt) {
        const float* kp = kh + (size_t)(jt * BN + srow0) * DH + klg * 8;
        ka[0][0] = *(const f32x4*)kp;
        ka[0][1] = *(const f32x4*)(kp + 4);
        kp += 32 * DH;
        ka[1][0] = *(const f32x4*)kp;
        ka[1][1] = *(const f32x4*)(kp + 4);
        const float* vpx = vh + (size_t)(jt * BN + kb) * DH + dr;
        #pragma unroll
        for (int ii = 0; ii < 4; ++ii) va[ii] = *(const f32x4*)(vpx + ii * DH);
    };
    auto commitKV = [&](int b) {
        #pragma unroll
        for (int s = 0; s < 2; ++s) {
            bf16x8 o;
            #pragma unroll
            for (int jj = 0; jj < 4; ++jj) {
                o[jj]     = (__bf16)ka[s][0][jj];
                o[4 + jj] = (__bf16)ka[s][1][jj];
            }
            *(bf16x8*)((char*)Ks[b] + s * 4096 + tid * 16) = o;
        }
        #pragma unroll
        for (int dd = 0; dd < 4; ++dd) {   // in-register 4x4 transpose, b64 out
            bf16x4 p4v;
            #pragma unroll
            for (int ii = 0; ii < 4; ++ii) p4v[ii] = (__bf16)va[ii][dd];
            *(bf16x4*)((char*)Vs[b] + (vwb ^ (dd << 4))) = p4v;
        }
    };

    // ---- prologue: tile jt0 -> buf0; issue loads for jt0+1 ----
    issueKV(jt0);
    commitKV(0);
    if (jt0 + 1 < jt_end) issueKV(jt0 + 1);
    __syncthreads();

    int buf = 0;
    for (int jt = jt0; jt < jt_end; ++jt) {
        // commit tile jt+1 (regs loaded a full iteration ago) into buf^1
        if (jt + 1 < jt_end) commitKV(buf ^ 1);
        // issue loads for tile jt+2
        if (jt + 2 < jt_end) issueKV(jt + 2);

        // ---- S^T = K * Q^T from buf ----
        const char* Kb = (const char*)Ks[buf];
        float s4[2][4][4];                 // [a][t][r], kv = jt*64+t*16+g*4+r
        __builtin_amdgcn_s_setprio(1);
        #pragma unroll
        for (int t = 0; t < 4; ++t) {
            f32x4 sa0 = {}, sa1 = {};
            #pragma unroll
            for (int c = 0; c < 2; ++c) {
                bf16x8 kf = *(const bf16x8*)(Kb +
                    (t * 16 + li) * 128 + (((c * 4 + g) ^ (li & 7)) << 4));
                sa0 = __builtin_amdgcn_mfma_f32_16x16x32_bf16(kf, qf[0][c], sa0, 0, 0, 0);
                sa1 = __builtin_amdgcn_mfma_f32_16x16x32_bf16(kf, qf[1][c], sa1, 0, 0, 0);
            }
            #pragma unroll
            for (int r = 0; r < 4; ++r) { s4[0][t][r] = sa0[r]; s4[1][t][r] = sa1[r]; }
        }
        __builtin_amdgcn_s_setprio(0);

        if (jt >= 2 * mt2) {               // diagonal region: causal mask
            #pragma unroll
            for (int a = 0; a < 2; ++a) {
                const int qr = q0 + w * 32 + a * 16 + li;
                #pragma unroll
                for (int t = 0; t < 4; ++t) {
                    #pragma unroll
                    for (int r = 0; r < 4; ++r)
                        if (jt * 64 + t * 16 + g * 4 + r > qr) s4[a][t][r] = -1e30f;
                }
            }
        }

        // ---- p = 2^s -> packed b64 stores (4 consecutive kv per reg-quad) ----
        #pragma unroll
        for (int a = 0; a < 2; ++a) {
            const int row = a * 16 + li;
            #pragma unroll
            for (int t = 0; t < 4; ++t) {
                bf16x4 p4;
                #pragma unroll
                for (int r = 0; r < 4; ++r) p4[r] = (__bf16)EXP2F(s4[a][t][r]);
                const int pg = (t * 2 + (g >> 1)) ^ (li & 7);
                *(bf16x4*)((char*)Ps + w * 4096 + row * 128 + (pg << 4) + ((g & 1) << 3)) = p4;
            }
        }

        // ---- O += P V ; l += P * ones; V fragments: single b128 reads ----
        __builtin_amdgcn_s_setprio(1);
        #pragma unroll
        for (int c = 0; c < 2; ++c) {
            const int pgp = ((c * 4 + g) ^ (li & 7)) << 4;
            bf16x8 pf0 = *(const bf16x8*)((const char*)Ps + w * 4096 + li * 128 + pgp);
            bf16x8 pf1 = *(const bf16x8*)((const char*)Ps + w * 4096 + (16 + li) * 128 + pgp);
            accl[0] = __builtin_amdgcn_mfma_f32_16x16x32_bf16(pf0, ones, accl[0], 0, 0, 0);
            accl[1] = __builtin_amdgcn_mfma_f32_16x16x32_bf16(pf1, ones, accl[1], 0, 0, 0);
            #pragma unroll
            for (int t = 0; t < 4; ++t) {
                bf16x8 vf = *(const bf16x8*)((const char*)Vs[buf] +
                    ((((t * 2 + c) * 4 + g) << 8) | ((li ^ (g | (t << 2))) << 4)));
                acc[0][t] = __builtin_amdgcn_mfma_f32_16x16x32_bf16(pf0, vf, acc[0][t], 0, 0, 0);
                acc[1][t] = __builtin_amdgcn_mfma_f32_16x16x32_bf16(pf1, vf, acc[1][t], 0, 0, 0);
            }
        }
        __builtin_amdgcn_s_setprio(0);

        if (jt + 1 < jt_end) __syncthreads();   // readers of buf done; buf^1 ready
        buf ^= 1;
    }

    if (2 * mt2 + 2 <= 8) {
        // ---- single-chunk q-tile: normalize in-register, write out directly
        float* oh = out + (size_t)bh * SEQ * DH;
        #pragma unroll
        for (int a = 0; a < 2; ++a) {
            #pragma unroll
            for (int r = 0; r < 4; ++r) {
                const int row = q0 + w * 32 + a * 16 + g * 4 + r;
                const float inv = 1.0f / accl[a][r];
                float* op = oh + (size_t)row * DH + li;
                #pragma unroll
                for (int t = 0; t < 4; ++t) op[t * 16] = acc[a][t][r] * inv;
            }
        }
    } else {
        // ---- partials out (O in bf16; l in f32) ----
        const int slot = (bh * 16 + mt2) * 4 + chunk;
        __bf16* po = opart + (size_t)slot * 8192;
        #pragma unroll
        for (int a = 0; a < 2; ++a) {
            #pragma unroll
            for (int r = 0; r < 4; ++r) {
                const int row = w * 32 + a * 16 + g * 4 + r;
                __bf16* op = po + row * 64 + li;
                #pragma unroll
                for (int t = 0; t < 4; ++t) op[t * 16] = (__bf16)acc[a][t][r];
                if (li == 0) lpart[(size_t)slot * 128 + row] = accl[a][r];
            }
        }
    }
}

// ---------------- reduce: sum bf16 chunks, normalize (mt2 >= 4 only) ----------------
__global__ __launch_bounds__(256)
void fa_reduce(const __bf16* __restrict__ opart, const float* __restrict__ lpart,
               float* __restrict__ out)
{
    const int bx = blockIdx.x;             // 288 = 8 XCDs x 3 headgrp x 12
    const int xcd = bx & 7;
    const int r2 = bx >> 3;                // 0..35
    const int bh = (r2 / 12) * 8 + xcd;    // co-locate with producer XCD
    const int mt2 = 4 + (r2 % 12);
    const int nc = (mt2 >> 2) + 1;         // ceil((2*mt2+2)/8)
    const int base = (bh * 16 + mt2) * 4;
    const int tid = threadIdx.x;
    #pragma unroll
    for (int rnd = 0; rnd < 8; ++rnd) {
        const int flat = rnd * 1024 + tid * 4;
        const int row = flat >> 6;
        float o0 = 0, o1 = 0, o2 = 0, o3 = 0, l = 0;
        for (int c = 0; c < nc; ++c) {
            bf16x4 ov = *(const bf16x4*)(opart + (size_t)(base + c) * 8192 + flat);
            o0 += (float)ov[0]; o1 += (float)ov[1]; o2 += (float)ov[2]; o3 += (float)ov[3];
            l += lpart[(size_t)(base + c) * 128 + row];
        }
        const float inv = 1.0f / l;
        f32x4 res = { o0 * inv, o1 * inv, o2 * inv, o3 * inv };
        *(f32x4*)(out + (size_t)bh * SEQ * DH + (size_t)mt2 * 8192 + flat) = res;
    }
}

// ---------------- fallback: R1 self-contained kernel ----------------
__global__ __launch_bounds__(256, 2)
void fa_causal_kernel(const float* __restrict__ q, const float* __restrict__ k,
                      const float* __restrict__ v, float* __restrict__ out)
{
    const int mt = 31 - (blockIdx.x & 31);
    const int bh = blockIdx.x >> 5;
    const int tid = threadIdx.x;
    const int w = tid >> 6, lane = tid & 63;
    const int g = lane >> 4, li = lane & 15;
    const int m0 = mt * 64;
    __shared__ __bf16 KsF[BN][LDK];
    __shared__ __bf16 VsF[DH][LDK];
    __shared__ __bf16 PsF[4][16][LDK];
    const size_t head_off = (size_t)bh * SEQ * DH;
    const float* qh = q + head_off;
    const float* kh = k + head_off;
    const float* vh = v + head_off;
    float* oh = out + head_off;
    const int qrow = m0 + w * 16 + li;
    bf16x8 qf[2];
    {
        const float* qp = qh + (size_t)qrow * DH + g * 8;
        #pragma unroll
        for (int c = 0; c < 2; ++c) {
            const float* p = qp + c * 32;
            #pragma unroll
            for (int jj = 0; jj < 8; ++jj) qf[c][jj] = (__bf16)p[jj];
        }
    }
    f32x4 acc[4] = {};
    float mrow[4], lrow[4];
    #pragma unroll
    for (int r = 0; r < 4; ++r) { mrow[r] = -1e30f; lrow[r] = 0.0f; }
    const float scale = 0.125f;
    const int srow = tid >> 2, scol = (tid & 3) * 16;
    for (int jt = 0; jt <= mt; ++jt) {
        const int kv0 = jt * BN;
        __syncthreads();
        {
            const float* kp = kh + (size_t)(kv0 + srow) * DH + scol;
            __bf16 tmp[16];
            #pragma unroll
            for (int jj = 0; jj < 16; ++jj) tmp[jj] = (__bf16)kp[jj];
            *(bf16x8*)&KsF[srow][scol]     = *(bf16x8*)&tmp[0];
            *(bf16x8*)&KsF[srow][scol + 8] = *(bf16x8*)&tmp[8];
            const float* vp = vh + (size_t)(kv0 + srow) * DH + scol;
            #pragma unroll
            for (int jj = 0; jj < 16; ++jj) VsF[scol + jj][srow] = (__bf16)vp[jj];
        }
        __syncthreads();
        float s4[4][4];
        #pragma unroll
        for (int t = 0; t < 4; ++t) {
            f32x4 sa = {};
            #pragma unroll
            for (int c = 0; c < 2; ++c) {
                bf16x8 kfr = *(const bf16x8*)&KsF[t * 16 + li][c * 32 + g * 8];
                sa = __builtin_amdgcn_mfma_f32_16x16x32_bf16(qf[c], kfr, sa, 0, 0, 0);
            }
            #pragma unroll
            for (int r = 0; r < 4; ++r) s4[t][r] = sa[r] * scale;
        }
        if (jt == mt) {
            #pragma unroll
            for (int t = 0; t < 4; ++t) {
                const int col = kv0 + t * 16 + li;
                #pragma unroll
                for (int r = 0; r < 4; ++r)
                    if (col > m0 + w * 16 + g * 4 + r) s4[t][r] = -1e30f;
            }
        }
        #pragma unroll
        for (int r = 0; r < 4; ++r) {
            float mx = fmaxf(fmaxf(s4[0][r], s4[1][r]), fmaxf(s4[2][r], s4[3][r]));
            #pragma unroll
            for (int off = 1; off < 16; off <<= 1)
                mx = fmaxf(mx, __shfl_xor(mx, off, 64));
            const float mnew = fmaxf(mrow[r], mx);
            const float alpha = __expf(mrow[r] - mnew);
            mrow[r] = mnew;
            float ps = 0.0f;
            #pragma unroll
            for (int t = 0; t < 4; ++t) {
                const float p = __expf(s4[t][r] - mnew);
                s4[t][r] = p;
                ps += p;
            }
            #pragma unroll
            for (int off = 1; off < 16; off <<= 1)
                ps += __shfl_xor(ps, off, 64);
            lrow[r] = lrow[r] * alpha + ps;
            #pragma unroll
            for (int t = 0; t < 4; ++t) acc[t][r] *= alpha;
        }
        #pragma unroll
        for (int t = 0; t < 4; ++t)
            #pragma unroll
            for (int r = 0; r < 4; ++r)
                PsF[w][g * 4 + r][t * 16 + li] = (__bf16)s4[t][r];
        __syncthreads();
        #pragma unroll
        for (int c = 0; c < 2; ++c) {
            bf16x8 pf = *(const bf16x8*)&PsF[w][li][c * 32 + g * 8];
            #pragma unroll
            for (int t = 0; t < 4; ++t) {
                bf16x8 vfr = *(const bf16x8*)&VsF[t * 16 + li][c * 32 + g * 8];
                acc[t] = __builtin_amdgcn_mfma_f32_16x16x32_bf16(pf, vfr, acc[t], 0, 0, 0);
            }
        }
    }
    #pragma unroll
    for (int r = 0; r < 4; ++r) {
        const int row = m0 + w * 16 + g * 4 + r;
        const float inv = 1.0f / lrow[r];
        float* op = oh + (size_t)row * DH + li;
        #pragma unroll
        for (int t = 0; t < 4; ++t) op[t * 16] = acc[t][r] * inv;
    }
}

extern "C" void kernel_launch(void* const* d_in, const int* in_sizes, int n_in,
                              void* d_out, int out_size, void* d_ws, size_t ws_size,
                              hipStream_t stream) {
    (void)in_sizes; (void)n_in; (void)out_size;
    const float* q = (const float*)d_in[0];
    const float* k = (const float*)d_in[1];
    const float* v = (const float*)d_in[2];
    float* out = (float*)d_out;

    if (ws_size >= WS_FA14) {
        __bf16* opart = (__bf16*)d_ws;
        float* lpart = (float*)((char*)d_ws + (size_t)NSLOT * 8192 * 2);
        fa16_kernel<<<dim3(960), dim3(256), 0, stream>>>(q, k, v, opart, lpart, out);
        fa_reduce<<<dim3(288), dim3(256), 0, stream>>>(opart, lpart, out);
    } else {
        fa_causal_kernel<<<dim3(NHEADS * 32), dim3(256), 0, stream>>>(q, k, v, out);
    }
}